// Round 7
// baseline (184.779 us; speedup 1.0000x reference)
//
#include <hip/hip_runtime.h>

#define LMBDA 0.001f
#define NS_SY 4      // NS iters for inv(sy) (first iter analytic)
#define NS_SX 5      // NS iters for inv(sx) (first iter analytic)
#define OUTER_FULL 2 // full Richardson iters after free X1 = FyAT*Ginv (== old OUTER=3)
#define LDP 68       // padded stride
#define GYS_A 40     // A-gemm k-strides (160 blocks, 2 chunks each)
#define GYS_F 19     // Fy-gemm k-strides (76 blocks, 4-5 chunks each)

// workspace layout (float offsets) — [0, 40960) is memset to 0 each launch
#define WS_A    0        // 64*256 (atomic-accumulated)
#define WS_FY   16384    // 64*256 (atomic-accumulated)
#define WS_G1   32768    // 64*64  (atomic-accumulated by 4 chunk blocks)
#define WS_FYAT 36864    // 64*64  (atomic-accumulated by 4 chunk blocks)
#define WS_T1   40960
#define WS_R2   45056
#define WS_R4   49152
#define WS_C    53248
#define WS_FLAGS 57344   // ints: [0..3] A cols (GYS_A) [4..7] Fy cols (GYS_F)
                         //       [8] G1 chunks (4) [9] preps (6)

#define FMA4(ar, xs, b) { ar[0]=fmaf((xs),(b).x,ar[0]); ar[1]=fmaf((xs),(b).y,ar[1]); \
                          ar[2]=fmaf((xs),(b).z,ar[2]); ar[3]=fmaf((xs),(b).w,ar[3]); }
#define COMP(v,q) ((q)==0?(v).x:((q)==1?(v).y:((q)==2?(v).z:(v).w)))

// 256t: C-tile += A[4ti..][:] * B[:][4tj..]
template<int SA, int SB>
__device__ __forceinline__ void mm64(const float* __restrict__ A,
                                     const float* __restrict__ B,
                                     int ti, int tj, float a[4][4]) {
    #pragma unroll 4
    for (int k = 0; k < 64; k += 4) {
        float4 av0 = *(const float4*)&A[(4 * ti + 0) * SA + k];
        float4 av1 = *(const float4*)&A[(4 * ti + 1) * SA + k];
        float4 av2 = *(const float4*)&A[(4 * ti + 2) * SA + k];
        float4 av3 = *(const float4*)&A[(4 * ti + 3) * SA + k];
        float4 b0 = *(const float4*)&B[(k + 0) * SB + 4 * tj];
        float4 b1 = *(const float4*)&B[(k + 1) * SB + 4 * tj];
        float4 b2 = *(const float4*)&B[(k + 2) * SB + 4 * tj];
        float4 b3 = *(const float4*)&B[(k + 3) * SB + 4 * tj];
        FMA4(a[0], av0.x, b0); FMA4(a[0], av0.y, b1); FMA4(a[0], av0.z, b2); FMA4(a[0], av0.w, b3);
        FMA4(a[1], av1.x, b0); FMA4(a[1], av1.y, b1); FMA4(a[1], av1.z, b2); FMA4(a[1], av1.w, b3);
        FMA4(a[2], av2.x, b0); FMA4(a[2], av2.y, b1); FMA4(a[2], av2.z, b2); FMA4(a[2], av2.w, b3);
        FMA4(a[3], av3.x, b0); FMA4(a[3], av3.y, b1); FMA4(a[3], av3.z, b2); FMA4(a[3], av3.w, b3);
    }
}

// 128t: rows 4ti+r (ti=tid>>3, 0..15), cols 8tj..8tj+7 (tj=tid&7).
// 384 LDS wave-instr per mm (vs 512 at 256t) -> 1.92us vs 2.56us when LDS-bound.
// Per-element FMA order identical to mm64 (k asc, q 0..3) -> bit-identical.
template<int SA, int SB>
__device__ __forceinline__ void mm64h(const float* __restrict__ A,
                                      const float* __restrict__ B,
                                      int ti, int tj, float a[4][8]) {
    #pragma unroll 4
    for (int k = 0; k < 64; k += 4) {
        float4 av[4];
        #pragma unroll
        for (int r = 0; r < 4; ++r) av[r] = *(const float4*)&A[(4 * ti + r) * SA + k];
        #pragma unroll
        for (int q = 0; q < 4; ++q) {
            float4 b0 = *(const float4*)&B[(k + q) * SB + 8 * tj];
            float4 b1 = *(const float4*)&B[(k + q) * SB + 8 * tj + 4];
            #pragma unroll
            for (int r = 0; r < 4; ++r) {
                float x = COMP(av[r], q);
                FMA4(a[r], x, b0);
                FMA4((a[r] + 4), x, b1);
            }
        }
    }
}

// dot-style 4x4: a[r][c] += A[4ti+r][:] . B[4tj+c][:]
template<int SA, int SB>
__device__ __forceinline__ void mmdot(const float* __restrict__ A,
                                      const float* __restrict__ B,
                                      int ti, int tj, float a[4][4]) {
    #pragma unroll 4
    for (int m = 0; m < 64; m += 4) {
        float4 av[4], bv[4];
        #pragma unroll
        for (int r = 0; r < 4; ++r) av[r] = *(const float4*)&A[(4 * ti + r) * SA + m];
        #pragma unroll
        for (int c = 0; c < 4; ++c) bv[c] = *(const float4*)&B[(4 * tj + c) * SB + m];
        #pragma unroll
        for (int r = 0; r < 4; ++r)
            #pragma unroll
            for (int c = 0; c < 4; ++c)
                a[r][c] += av[r].x * bv[c].x + av[r].y * bv[c].y
                         + av[r].z * bv[c].z + av[r].w * bv[c].w;
    }
}

// Newton-Schulz (classic, b0/b2): X <- X(2I - M X), first iter analytic.
template<int SM>
__device__ __forceinline__ void ns_invert(const float* sM, float* sX, float* sY,
                                          int iters, int ti, int tj,
                                          int tid, float alpha)
{
    const float a2 = alpha * alpha;
    for (int idx = tid; idx < 4096; idx += 256) {
        int i = idx >> 6, j = idx & 63;
        sX[i * LDP + j] = ((i == j) ? 2.f * alpha : 0.f) - a2 * sM[i * SM + j];
    }
    __syncthreads();
    for (int it = 1; it < iters; ++it) {
        float y[4][4] = {};
        mm64<SM, LDP>(sM, sX, ti, tj, y);          // Y = M*X
        #pragma unroll
        for (int r = 0; r < 4; ++r) {
            float4 v = {y[r][0], y[r][1], y[r][2], y[r][3]};
            *(float4*)&sY[(4 * ti + r) * 64 + 4 * tj] = v;
        }
        __syncthreads();
        float z[4][4] = {};
        mm64<LDP, 64>(sX, sY, ti, tj, z);           // Z = X*Y
        __syncthreads();
        #pragma unroll
        for (int r = 0; r < 4; ++r) {
            float4 xv = *(const float4*)&sX[(4 * ti + r) * LDP + 4 * tj];
            xv.x = 2.f * xv.x - z[r][0];
            xv.y = 2.f * xv.y - z[r][1];
            xv.z = 2.f * xv.z - z[r][2];
            xv.w = 2.f * xv.w - z[r][3];
            *(float4*)&sX[(4 * ti + r) * LDP + 4 * tj] = xv;
        }
        __syncthreads();
    }
}

// Residual-form NS fused pass (256t, FMA-bound): Xd = Xs + Xs*Rs ; Rd = Rs*Rs.
__device__ __forceinline__ void ns_pass_d(const float* Xs, const float* Rs,
                                          float* Xd, float* Rd, int ti, int tj)
{
    float xr[4][4] = {}, rr[4][4] = {};
    #pragma unroll 4
    for (int k = 0; k < 64; k += 4) {
        float4 xa[4], ra[4];
        #pragma unroll
        for (int r = 0; r < 4; ++r) {
            xa[r] = *(const float4*)&Xs[(4 * ti + r) * LDP + k];
            ra[r] = *(const float4*)&Rs[(4 * ti + r) * LDP + k];
        }
        #pragma unroll
        for (int q = 0; q < 4; ++q) {
            float4 bv = *(const float4*)&Rs[(k + q) * LDP + 4 * tj];
            #pragma unroll
            for (int r = 0; r < 4; ++r) {
                FMA4(xr[r], COMP(xa[r], q), bv);
                FMA4(rr[r], COMP(ra[r], q), bv);
            }
        }
    }
    #pragma unroll
    for (int r = 0; r < 4; ++r) {
        float4 xo = *(const float4*)&Xs[(4 * ti + r) * LDP + 4 * tj];
        float4 xn = {xo.x + xr[r][0], xo.y + xr[r][1],
                     xo.z + xr[r][2], xo.w + xr[r][3]};
        *(float4*)&Xd[(4 * ti + r) * LDP + 4 * tj] = xn;
        float4 rv = {rr[r][0], rr[r][1], rr[r][2], rr[r][3]};
        *(float4*)&Rd[(4 * ti + r) * LDP + 4 * tj] = rv;
    }
    __syncthreads();
}

// ---- device-scope producer/consumer handoff ------------------------------
__device__ __forceinline__ void wait_ge(int* flag, int target, int tid) {
    if (tid == 0) {
        while (__hip_atomic_load(flag, __ATOMIC_ACQUIRE, __HIP_MEMORY_SCOPE_AGENT) < target)
            __builtin_amdgcn_s_sleep(8);
    }
    __syncthreads();
    __threadfence();
}

__device__ __forceinline__ void signal_one(int* flag, int tid) {
    __syncthreads();
    __threadfence();
    if (tid == 0)
        (void)__hip_atomic_fetch_add(flag, 1, __ATOMIC_RELEASE, __HIP_MEMORY_SCOPE_AGENT);
}

// ---------------- single fused kernel, 247 co-resident blocks, 256 thr ----
// 0..159  : A-gemm  (gx=bid&3 col, gy=bid>>2 over GYS_A k-strides, 2 chunks)
// 160..235: Fy-gemm (gx=(bid-160)&3, gy=(bid-160)>>2 over GYS_F, 4-5 chunks)
// 236..239: G1 chunk ch = A_ch A_ch^T -> atomicAdd (waits flags[ch]==GYS_A)
// 240..243: FyAT chunk ch -> atomicAdd (waits flags[ch], flags[4+ch])
// 244: b0 sy chain   245: b2 sx chain
// 246: solve = Frobenius + residual-NS(G1) + free-X1 + 2 full Richardson
__global__ __launch_bounds__(256, 1) void fused_fmnet(
    const float* __restrict__ fx, const float* __restrict__ fy,
    const float* __restrict__ ex, const float* __restrict__ ey,
    const float* __restrict__ tx, const float* __restrict__ ty,
    const float* __restrict__ sx, const float* __restrict__ sy,
    float* __restrict__ ws, float* __restrict__ out)
{
    extern __shared__ __align__(16) float lds[];
    int* flags = (int*)(ws + WS_FLAGS);
    const int tid = threadIdx.x;
    const int ti = tid >> 4, tj = tid & 15;   // 256t mapping
    const int bid = blockIdx.x;

    if (bid < 236) {
        // ---------------- GEMM: 64x64 (mat,m0) tile, k-strided by gy ----
        float* sT = lds;            // sT[v][k] (transposed stage)
        float* sF = lds + 4352;     // sF[v][m]
        int mat, gx, gy, gstride;
        if (bid < 160) { mat = 0; gx = bid & 3; gy = bid >> 2; gstride = GYS_A; }
        else { int b2 = bid - 160; mat = 1; gx = b2 & 3; gy = b2 >> 2; gstride = GYS_F; }
        const int m0 = gx << 6;
        const float* __restrict__ T = mat ? ty : tx;
        const float* __restrict__ F = mat ? fy : fx;
        float* __restrict__ Out = ws + (mat ? WS_FY : WS_A);

        float4 tv[4], fv[4];
        int sc = gy;
        int vlen = 5000 - (sc << 6); if (vlen > 64) vlen = 64;
        #pragma unroll
        for (int w = 0; w < 4; ++w) {
            const int fidx = tid + (w << 8);
            const int row = fidx >> 4, q = fidx & 15, vv = q << 2;
            if (vv < vlen) tv[w] = *(const float4*)(T + (size_t)row * 5000 + (sc << 6) + vv);
            if (row < vlen) fv[w] = *(const float4*)(F + (size_t)((sc << 6) + row) * 256 + m0 + (q << 2));
        }
        #pragma unroll
        for (int w = 0; w < 4; ++w) {
            const int fidx = tid + (w << 8);
            const int row = fidx >> 4, q = fidx & 15, vv = q << 2;
            if (vv < vlen) {
                sT[(vv + 0) * LDP + row] = tv[w].x;
                sT[(vv + 1) * LDP + row] = tv[w].y;
                sT[(vv + 2) * LDP + row] = tv[w].z;
                sT[(vv + 3) * LDP + row] = tv[w].w;
            }
            if (row < vlen) *(float4*)&sF[row * LDP + (q << 2)] = fv[w];
        }
        __syncthreads();

        float acc[4][4] = {};
        for (;;) {
            const int nsc = sc + gstride;
            int nvlen = 5000 - (nsc << 6);
            if (nvlen > 64) nvlen = 64;
            if (nvlen > 0) {   // prefetch next chunk into regs
                #pragma unroll
                for (int w = 0; w < 4; ++w) {
                    const int fidx = tid + (w << 8);
                    const int row = fidx >> 4, q = fidx & 15, vv = q << 2;
                    if (vv < nvlen) tv[w] = *(const float4*)(T + (size_t)row * 5000 + (nsc << 6) + vv);
                    if (row < nvlen) fv[w] = *(const float4*)(F + (size_t)((nsc << 6) + row) * 256 + m0 + (q << 2));
                }
            }
            #pragma unroll 4
            for (int v = 0; v < vlen; ++v) {
                float4 av = *(const float4*)&sT[v * LDP + 4 * ti];
                float4 bv = *(const float4*)&sF[v * LDP + 4 * tj];
                FMA4(acc[0], av.x, bv); FMA4(acc[1], av.y, bv);
                FMA4(acc[2], av.z, bv); FMA4(acc[3], av.w, bv);
            }
            if (nvlen <= 0) break;
            __syncthreads();
            #pragma unroll
            for (int w = 0; w < 4; ++w) {
                const int fidx = tid + (w << 8);
                const int row = fidx >> 4, q = fidx & 15, vv = q << 2;
                if (vv < nvlen) {
                    sT[(vv + 0) * LDP + row] = tv[w].x;
                    sT[(vv + 1) * LDP + row] = tv[w].y;
                    sT[(vv + 2) * LDP + row] = tv[w].z;
                    sT[(vv + 3) * LDP + row] = tv[w].w;
                }
                if (row < nvlen) *(float4*)&sF[row * LDP + (q << 2)] = fv[w];
            }
            __syncthreads();
            sc = nsc; vlen = nvlen;
        }
        #pragma unroll
        for (int r = 0; r < 4; ++r)
            #pragma unroll
            for (int c = 0; c < 4; ++c)
                atomicAdd(&Out[(4 * ti + r) * 256 + m0 + 4 * tj + c], acc[r][c]);
        __syncthreads();
        __threadfence();
        if (tid == 0)
            (void)__hip_atomic_fetch_add(&flags[mat * 4 + gx], 1, __ATOMIC_RELEASE, __HIP_MEMORY_SCOPE_AGENT);
    } else if (bid < 240) {
        // ---------------- G1 chunk: A_ch A_ch^T -> atomicAdd WS_G1 ----
        const int ch = bid - 236;
        wait_ge(&flags[ch], GYS_A, tid);
        float* sA = lds;             // pad
        for (int idx = tid; idx < 1024; idx += 256) {
            int i = idx >> 4, m4 = (idx & 15) << 2;
            *(float4*)&sA[i * LDP + m4] =
                *(const float4*)&ws[WS_A + i * 256 + (ch << 6) + m4];
        }
        __syncthreads();
        float a[4][4] = {};
        mmdot<LDP, LDP>(sA, sA, ti, tj, a);
        #pragma unroll
        for (int r = 0; r < 4; ++r)
            #pragma unroll
            for (int c = 0; c < 4; ++c)
                atomicAdd(&ws[WS_G1 + (4 * ti + r) * 64 + 4 * tj + c], a[r][c]);
        __syncthreads();
        __threadfence();
        if (tid == 0)
            (void)__hip_atomic_fetch_add(&flags[8], 1, __ATOMIC_RELEASE, __HIP_MEMORY_SCOPE_AGENT);
    } else if (bid < 244) {
        // ---------------- FyAT chunk: Fy_ch A_ch^T -> atomicAdd WS_FYAT ----
        const int ch = bid - 240;
        wait_ge(&flags[ch], GYS_A, tid);
        wait_ge(&flags[4 + ch], GYS_F, tid);
        float* sFy = lds;            // pad
        float* sAx = lds + 4352;     // pad
        for (int idx = tid; idx < 1024; idx += 256) {
            int i = idx >> 4, m4 = (idx & 15) << 2;
            *(float4*)&sFy[i * LDP + m4] = *(const float4*)&ws[WS_FY + i * 256 + (ch << 6) + m4];
            *(float4*)&sAx[i * LDP + m4] = *(const float4*)&ws[WS_A  + i * 256 + (ch << 6) + m4];
        }
        __syncthreads();
        float a[4][4] = {};
        mmdot<LDP, LDP>(sFy, sAx, ti, tj, a);
        #pragma unroll
        for (int r = 0; r < 4; ++r)
            #pragma unroll
            for (int c = 0; c < 4; ++c)
                atomicAdd(&ws[WS_FYAT + (4 * ti + r) * 64 + 4 * tj + c], a[r][c]);
        signal_one(&flags[9], tid);
    } else if (bid == 244) {
        // ---------------- b0: sy chain (no deps) ----------------
        float* sSy = lds;            // pad: sy, later Hinv
        float* sXx = lds + 4352;     // pad: NS X -> Sinv
        float* sYy = lds + 8704;     // flat: NS tmp
        float* sH  = lds + 12800;    // flat: H1
        float* sV  = lds + 16896;    // ey
        for (int idx = tid; idx < 1024; idx += 256) {
            int i = idx >> 4, j4 = (idx & 15) << 2;
            *(float4*)&sSy[i * LDP + j4] = *(const float4*)&sy[i * 64 + j4];
        }
        if (tid < 64) sV[tid] = ey[tid];
        __syncthreads();
        // H1 = sy^T sy (column outer-product)
        {
            float h[4][4] = {};
            for (int k = 0; k < 64; ++k) {
                float4 av = *(const float4*)&sSy[k * LDP + 4 * ti];
                float4 bv = *(const float4*)&sSy[k * LDP + 4 * tj];
                FMA4(h[0], av.x, bv); FMA4(h[1], av.y, bv);
                FMA4(h[2], av.z, bv); FMA4(h[3], av.w, bv);
            }
            #pragma unroll
            for (int r = 0; r < 4; ++r) {
                float4 v = {h[r][0], h[r][1], h[r][2], h[r][3]};
                *(float4*)&sH[(4 * ti + r) * 64 + 4 * tj] = v;
            }
        }
        __syncthreads();
        ns_invert<LDP>(sSy, sXx, sYy, NS_SY, ti, tj, tid, 1.0f);   // Sinv
        // Hinv = Sinv Sinv^T -> overwrite sSy
        {
            float h[4][4] = {};
            mmdot<LDP, LDP>(sXx, sXx, ti, tj, h);
            __syncthreads();
            #pragma unroll
            for (int r = 0; r < 4; ++r) {
                float4 v = {h[r][0], h[r][1], h[r][2], h[r][3]};
                *(float4*)&sSy[(4 * ti + r) * LDP + 4 * tj] = v;
            }
        }
        __syncthreads();
        // C = Hinv * (D H1)
        {
            float a[4][4] = {};
            #pragma unroll 4
            for (int k = 0; k < 64; k += 4) {
                float4 av[4];
                #pragma unroll
                for (int r = 0; r < 4; ++r) av[r] = *(const float4*)&sSy[(4 * ti + r) * LDP + k];
                #pragma unroll
                for (int q = 0; q < 4; ++q) {
                    float e = sV[k + q];
                    float4 bv = *(const float4*)&sH[(k + q) * 64 + 4 * tj];
                    bv.x *= e; bv.y *= e; bv.z *= e; bv.w *= e;
                    #pragma unroll
                    for (int r = 0; r < 4; ++r) FMA4(a[r], COMP(av[r], q), bv);
                }
            }
            #pragma unroll
            for (int r = 0; r < 4; ++r) {
                float4 v = {a[r][0], a[r][1], a[r][2], a[r][3]};
                *(float4*)&ws[WS_C + (4 * ti + r) * 64 + 4 * tj] = v;
            }
        }
        signal_one(&flags[9], tid);
    } else if (bid == 245) {
        // ---------------- b2: sx chain (no deps) ----------------
        float* sM = lds;             // pad: sx
        float* sX = lds + 4352;      // pad: P
        float* sY = lds + 8704;      // flat
        float* sV = lds + 12800;     // ex
        for (int idx = tid; idx < 1024; idx += 256) {
            int i = idx >> 4, j4 = (idx & 15) << 2;
            *(float4*)&sM[i * LDP + j4] = *(const float4*)&sx[i * 64 + j4];
        }
        if (tid < 64) sV[tid] = ex[tid];
        __syncthreads();
        ns_invert<LDP>(sM, sX, sY, NS_SX, ti, tj, tid, 1.0f);
        float aR2[4][4] = {}, aR4[4][4] = {}, aT1[4][4] = {};
        for (int k = 0; k < 64; ++k) {
            float e = sV[k], e2 = e * e;
            float4 av = *(const float4*)&sX[k * LDP + 4 * ti];
            float4 bv = *(const float4*)&sX[k * LDP + 4 * tj];
            float avv[4] = {av.x, av.y, av.z, av.w};
            #pragma unroll
            for (int r = 0; r < 4; ++r) {
                FMA4(aR4[r], avv[r], bv);
                float ea = e * avv[r];
                FMA4(aR2[r], ea, bv);
                float e2a = e2 * avv[r];
                FMA4(aT1[r], e2a, bv);
            }
        }
        #pragma unroll
        for (int r = 0; r < 4; ++r) {
            int o = (4 * ti + r) * 64 + 4 * tj;
            float4 v2 = {aR2[r][0], aR2[r][1], aR2[r][2], aR2[r][3]};
            float4 v4 = {aR4[r][0], aR4[r][1], aR4[r][2], aR4[r][3]};
            float4 v1 = {aT1[r][0], aT1[r][1], aT1[r][2], aT1[r][3]};
            *(float4*)&ws[WS_R2 + o] = v2;
            *(float4*)&ws[WS_R4 + o] = v4;
            *(float4*)&ws[WS_T1 + o] = v1;
        }
        signal_one(&flags[9], tid);
    } else {
        // ---------------- solve: residual-NS(G1) + free-X1 + Richardson ----
        //   sM  0      flat 4096 : G1 -> M1 (in place)
        //   P1  4096   pad  4352 : R1,R3 / FyAT-stage / E2 / W
        //   P2  8448   pad  4352 : R0,R2,R4 / C
        //   P3  12800  pad  4352 : X1,X3,X5=Ginv (in place)
        //   P4  17152  pad  4352 : X2,X4 / Richardson X / E1
        //   cR2 21504  flat 4096
        //   cR4 25600  flat 4096
        float* sM  = lds;
        float* P1  = lds + 4096;
        float* P2  = lds + 8448;
        float* P3  = lds + 12800;
        float* P4  = lds + 17152;
        float* cR2 = lds + 21504;
        float* cR4 = lds + 25600;
        const int ti2 = tid >> 3, tj2 = tid & 7;   // 128t mapping (valid when tid<128)

        wait_ge(&flags[8], 4, tid);      // G1 complete
        for (int idx = tid; idx < 1024; idx += 256) {
            int i = idx >> 4, j4 = (idx & 15) << 2;
            *(float4*)&sM[i * 64 + j4] = *(const float4*)&ws[WS_G1 + i * 64 + j4];
        }
        __syncthreads();
        // Frobenius-optimal alpha = tr(G1)/||G1||_F^2 (scratch in P1)
        if (tid < 64) {
            float s = 0.f;
            for (int j4 = 0; j4 < 64; j4 += 4) {
                float4 v = *(const float4*)&sM[tid * 64 + j4];
                s += v.x * v.x + v.y * v.y + v.z * v.z + v.w * v.w;
            }
            P1[tid] = s;
            P1[64 + tid] = sM[tid * 64 + tid];
        }
        __syncthreads();
        float f2 = 0.f, tr = 0.f;
        for (int i = 0; i < 64; ++i) { f2 += P1[i]; tr += P1[64 + i]; }
        const float alpha = tr / f2, a2 = alpha * alpha;
        // analytic: X1 = 2a I - a^2 G -> P3 ; R0 = I - a G -> P2
        for (int idx = tid; idx < 4096; idx += 256) {
            int i = idx >> 6, j = idx & 63;
            float g = sM[i * 64 + j];
            float d = (i == j) ? 1.f : 0.f;
            P3[i * LDP + j] = 2.f * alpha * d - a2 * g;
            P2[i * LDP + j] = d - alpha * g;
        }
        __syncthreads();
        // R1 = R0^2 -> P1  (128t)
        if (tid < 128) {
            float z[4][8] = {};
            mm64h<LDP, LDP>(P2, P2, ti2, tj2, z);
            #pragma unroll
            for (int r = 0; r < 4; ++r) {
                *(float4*)&P1[(4 * ti2 + r) * LDP + 8 * tj2]     = *(float4*)&z[r][0];
                *(float4*)&P1[(4 * ti2 + r) * LDP + 8 * tj2 + 4] = *(float4*)&z[r][4];
            }
        }
        __syncthreads();
        // fused residual-NS (256t, FMA-bound): X_{k+1}=X_k(I+R_k), R_{k+1}=R_k^2
        ns_pass_d(P3, P1, P4, P2, ti, tj);   // X2->P4, R2->P2
        ns_pass_d(P4, P2, P3, P1, ti, tj);   // X3->P3, R3->P1
        ns_pass_d(P3, P1, P4, P2, ti, tj);   // X4->P4, R4->P2
        // final: X5 = X4 + X4*R4 -> P3 = Ginv  (128t, no R update)
        if (tid < 128) {
            float z[4][8] = {};
            mm64h<LDP, LDP>(P4, P2, ti2, tj2, z);
            #pragma unroll
            for (int r = 0; r < 4; ++r) {
                float4 x0 = *(const float4*)&P4[(4 * ti2 + r) * LDP + 8 * tj2];
                float4 x1 = *(const float4*)&P4[(4 * ti2 + r) * LDP + 8 * tj2 + 4];
                x0.x += z[r][0]; x0.y += z[r][1]; x0.z += z[r][2]; x0.w += z[r][3];
                x1.x += z[r][4]; x1.y += z[r][5]; x1.z += z[r][6]; x1.w += z[r][7];
                *(float4*)&P3[(4 * ti2 + r) * LDP + 8 * tj2]     = x0;
                *(float4*)&P3[(4 * ti2 + r) * LDP + 8 * tj2 + 4] = x1;
            }
        }
        wait_ge(&flags[9], 6, tid);      // b0, b2, 4 FyAT chunks done (barriers)
        // stage: M1 = G1 + l*T1 (in place); R2,R4 flats; C->P2; FyAT->P1
        for (int idx = tid; idx < 1024; idx += 256) {
            int i = idx >> 4, j4 = (idx & 15) << 2;
            int o = i * 64 + j4;
            float4 gv = *(const float4*)&sM[o];
            float4 t = *(const float4*)&ws[WS_T1 + o];
            gv.x = fmaf(LMBDA, t.x, gv.x); gv.y = fmaf(LMBDA, t.y, gv.y);
            gv.z = fmaf(LMBDA, t.z, gv.z); gv.w = fmaf(LMBDA, t.w, gv.w);
            *(float4*)&sM[o] = gv;
            *(float4*)&cR2[o] = *(const float4*)&ws[WS_R2 + o];
            *(float4*)&cR4[o] = *(const float4*)&ws[WS_R4 + o];
            *(float4*)&P2[i * LDP + j4] = *(const float4*)&ws[WS_C + o];
            *(float4*)&P1[i * LDP + j4] = *(const float4*)&ws[WS_FYAT + o];
        }
        // per-thread constants: grp1 (256t) needs ey rows; grp2 (128t) needs FyAT
        float4 eyv = *(const float4*)&ey[4 * ti];
        float eyr[4] = {eyv.x, eyv.y, eyv.z, eyv.w};
        float leyr[4];
        #pragma unroll
        for (int r = 0; r < 4; ++r) leyr[r] = LMBDA * eyr[r];
        float fyr[4][8], xreg[4][8];
        if (tid < 128) {
            #pragma unroll
            for (int r = 0; r < 4; ++r) {
                *(float4*)&fyr[r][0] = *(const float4*)&ws[WS_FYAT + (4 * ti2 + r) * 64 + 8 * tj2];
                *(float4*)&fyr[r][4] = *(const float4*)&ws[WS_FYAT + (4 * ti2 + r) * 64 + 8 * tj2 + 4];
            }
        }
        __syncthreads();

        // free iteration 0: X1 = FyAT * Ginv -> P4  (128t)
        if (tid < 128) {
            float dX[4][8] = {};
            mm64h<LDP, LDP>(P1, P3, ti2, tj2, dX);
            #pragma unroll
            for (int r = 0; r < 4; ++r) {
                #pragma unroll
                for (int c = 0; c < 8; ++c) xreg[r][c] = dX[r][c];
                *(float4*)&P4[(4 * ti2 + r) * LDP + 8 * tj2]     = *(float4*)&xreg[r][0];
                *(float4*)&P4[(4 * ti2 + r) * LDP + 8 * tj2 + 4] = *(float4*)&xreg[r][4];
            }
        }
        __syncthreads();

        for (int it = 0; it < OUTER_FULL; ++it) {
            // grp1 (256t): Sm=X*M1, S2=X*R2, S4=X*R4 (shared A-reads)
            {
                float Sm[4][4] = {}, S2[4][4] = {}, S4[4][4] = {};
                #pragma unroll 2
                for (int k = 0; k < 64; k += 4) {
                    float4 av[4];
                    #pragma unroll
                    for (int r = 0; r < 4; ++r)
                        av[r] = *(const float4*)&P4[(4 * ti + r) * LDP + k];
                    #pragma unroll
                    for (int q = 0; q < 4; ++q) {
                        float4 mv = *(const float4*)&sM[(k + q) * 64 + 4 * tj];
                        float4 qv = *(const float4*)&cR2[(k + q) * 64 + 4 * tj];
                        float4 rv = *(const float4*)&cR4[(k + q) * 64 + 4 * tj];
                        #pragma unroll
                        for (int r = 0; r < 4; ++r) {
                            float x = COMP(av[r], q);
                            FMA4(Sm[r], x, mv);
                            FMA4(S2[r], x, qv);
                            FMA4(S4[r], x, rv);
                        }
                    }
                }
                __syncthreads();   // P4 (X) reads and P1 (W/FyAT) reads all done
                #pragma unroll
                for (int r = 0; r < 4; ++r) {
                    float4 e2, e1;
                    e2.x = LMBDA * fmaf(eyr[r], S4[r][0], -S2[r][0]);
                    e2.y = LMBDA * fmaf(eyr[r], S4[r][1], -S2[r][1]);
                    e2.z = LMBDA * fmaf(eyr[r], S4[r][2], -S2[r][2]);
                    e2.w = LMBDA * fmaf(eyr[r], S4[r][3], -S2[r][3]);
                    *(float4*)&P1[(4 * ti + r) * LDP + 4 * tj] = e2;
                    e1.x = fmaf(-leyr[r], S2[r][0], Sm[r][0]);
                    e1.y = fmaf(-leyr[r], S2[r][1], Sm[r][1]);
                    e1.z = fmaf(-leyr[r], S2[r][2], Sm[r][2]);
                    e1.w = fmaf(-leyr[r], S2[r][3], Sm[r][3]);
                    *(float4*)&P4[(4 * ti + r) * LDP + 4 * tj] = e1;  // E1 (X lives in xreg)
                }
            }
            __syncthreads();
            // grp2 (128t): Z = C*E2 ; W = FyAT - E1 - Z -> P1
            float Z[4][8] = {};
            if (tid < 128)
                mm64h<LDP, LDP>(P2, P1, ti2, tj2, Z);
            __syncthreads();   // all E2 (P1) reads done before W overwrite
            if (tid < 128) {
                #pragma unroll
                for (int r = 0; r < 4; ++r) {
                    float4 e10 = *(const float4*)&P4[(4 * ti2 + r) * LDP + 8 * tj2];
                    float4 e11 = *(const float4*)&P4[(4 * ti2 + r) * LDP + 8 * tj2 + 4];
                    float4 w0, w1;
                    w0.x = fyr[r][0] - e10.x - Z[r][0];
                    w0.y = fyr[r][1] - e10.y - Z[r][1];
                    w0.z = fyr[r][2] - e10.z - Z[r][2];
                    w0.w = fyr[r][3] - e10.w - Z[r][3];
                    w1.x = fyr[r][4] - e11.x - Z[r][4];
                    w1.y = fyr[r][5] - e11.y - Z[r][5];
                    w1.z = fyr[r][6] - e11.z - Z[r][6];
                    w1.w = fyr[r][7] - e11.w - Z[r][7];
                    *(float4*)&P1[(4 * ti2 + r) * LDP + 8 * tj2]     = w0;
                    *(float4*)&P1[(4 * ti2 + r) * LDP + 8 * tj2 + 4] = w1;
                }
            }
            __syncthreads();
            // grp3 (128t): dX = W*Ginv ; X += dX -> P4 (and out on last iter)
            if (tid < 128) {
                float dX[4][8] = {};
                mm64h<LDP, LDP>(P1, P3, ti2, tj2, dX);
                #pragma unroll
                for (int r = 0; r < 4; ++r) {
                    #pragma unroll
                    for (int c = 0; c < 8; ++c) xreg[r][c] += dX[r][c];
                    *(float4*)&P4[(4 * ti2 + r) * LDP + 8 * tj2]     = *(float4*)&xreg[r][0];
                    *(float4*)&P4[(4 * ti2 + r) * LDP + 8 * tj2 + 4] = *(float4*)&xreg[r][4];
                    if (it == OUTER_FULL - 1) {
                        *(float4*)&out[(4 * ti2 + r) * 64 + 8 * tj2]     = *(float4*)&xreg[r][0];
                        *(float4*)&out[(4 * ti2 + r) * 64 + 8 * tj2 + 4] = *(float4*)&xreg[r][4];
                    }
                }
            }
            if (it == OUTER_FULL - 1) break;
            __syncthreads();
        }
    }
}

extern "C" void kernel_launch(void* const* d_in, const int* in_sizes, int n_in,
                              void* d_out, int out_size, void* d_ws, size_t ws_size,
                              hipStream_t stream) {
    (void)in_sizes; (void)n_in; (void)out_size; (void)ws_size;
    const float* fx = (const float*)d_in[0];
    const float* fy = (const float*)d_in[1];
    const float* ex = (const float*)d_in[2];
    const float* ey = (const float*)d_in[3];
    const float* tx = (const float*)d_in[4];
    const float* ty = (const float*)d_in[5];
    const float* sx = (const float*)d_in[6];
    const float* sy = (const float*)d_in[7];
    float* ws = (float*)d_ws;
    float* out = (float*)d_out;

    (void)hipFuncSetAttribute((const void*)fused_fmnet,
                              hipFuncAttributeMaxDynamicSharedMemorySize, 134144);

    // zero A/Fy/G1/FyAT accumulators + flags
    (void)hipMemsetAsync(d_ws, 0, (size_t)(WS_T1) * sizeof(float), stream);
    (void)hipMemsetAsync((char*)d_ws + (size_t)WS_FLAGS * sizeof(float), 0, 64, stream);
    fused_fmnet<<<247, 256, 134144, stream>>>(fx, fy, ex, ey, tx, ty, sx, sy, ws, out);
}

// Round 8
// 168.207 us; speedup vs baseline: 1.0985x; 1.0985x over previous
//
#include <hip/hip_runtime.h>

#define LMBDA 0.001f
#define NS_SY 4      // NS iters for inv(sy) (first iter analytic)
#define NS_SX 5      // NS iters for inv(sx) (first iter analytic)
#define OUTER_FULL 2 // full Richardson iters after free X1 = FyAT*Ginv (== old OUTER=3)
#define LDP 68       // padded stride
#define GYS_A 40     // A-gemm k-strides (160 blocks, 2 chunks each) — A gates the serial chain
#define GYS_F 19     // Fy-gemm k-strides (76 blocks, 4-5 chunks) — FyAT needed ~20us later

// workspace layout (float offsets) — [0, 40960) is memset to 0 each launch
#define WS_A    0        // 64*256 (atomic-accumulated)
#define WS_FY   16384    // 64*256 (atomic-accumulated)
#define WS_G1   32768    // 64*64  (atomic-accumulated by 4 chunk blocks)
#define WS_FYAT 36864    // 64*64  (atomic-accumulated by 4 chunk blocks)
#define WS_T1   40960
#define WS_R2   45056
#define WS_R4   49152
#define WS_C    53248
#define WS_FLAGS 57344   // ints: [0..3] A cols (GYS_A) [4..7] Fy cols (GYS_F)
                         //       [8] G1 chunks (4) [9] preps (6)

#define FMA4(ar, xs, b) { ar[0]=fmaf((xs),(b).x,ar[0]); ar[1]=fmaf((xs),(b).y,ar[1]); \
                          ar[2]=fmaf((xs),(b).z,ar[2]); ar[3]=fmaf((xs),(b).w,ar[3]); }
#define COMP(v,q) ((q)==0?(v).x:((q)==1?(v).y:((q)==2?(v).z:(v).w)))

// C-tile += A[4ti..][:] * B[:][4tj..]; all f4 (b128) LDS reads
template<int SA, int SB>
__device__ __forceinline__ void mm64(const float* __restrict__ A,
                                     const float* __restrict__ B,
                                     int ti, int tj, float a[4][4]) {
    #pragma unroll 4
    for (int k = 0; k < 64; k += 4) {
        float4 av0 = *(const float4*)&A[(4 * ti + 0) * SA + k];
        float4 av1 = *(const float4*)&A[(4 * ti + 1) * SA + k];
        float4 av2 = *(const float4*)&A[(4 * ti + 2) * SA + k];
        float4 av3 = *(const float4*)&A[(4 * ti + 3) * SA + k];
        float4 b0 = *(const float4*)&B[(k + 0) * SB + 4 * tj];
        float4 b1 = *(const float4*)&B[(k + 1) * SB + 4 * tj];
        float4 b2 = *(const float4*)&B[(k + 2) * SB + 4 * tj];
        float4 b3 = *(const float4*)&B[(k + 3) * SB + 4 * tj];
        FMA4(a[0], av0.x, b0); FMA4(a[0], av0.y, b1); FMA4(a[0], av0.z, b2); FMA4(a[0], av0.w, b3);
        FMA4(a[1], av1.x, b0); FMA4(a[1], av1.y, b1); FMA4(a[1], av1.z, b2); FMA4(a[1], av1.w, b3);
        FMA4(a[2], av2.x, b0); FMA4(a[2], av2.y, b1); FMA4(a[2], av2.z, b2); FMA4(a[2], av2.w, b3);
        FMA4(a[3], av3.x, b0); FMA4(a[3], av3.y, b1); FMA4(a[3], av3.z, b2); FMA4(a[3], av3.w, b3);
    }
}

// dot-style 4x4: a[r][c] += A[4ti+r][:] . B[4tj+c][:]
template<int SA, int SB>
__device__ __forceinline__ void mmdot(const float* __restrict__ A,
                                      const float* __restrict__ B,
                                      int ti, int tj, float a[4][4]) {
    #pragma unroll 4
    for (int m = 0; m < 64; m += 4) {
        float4 av[4], bv[4];
        #pragma unroll
        for (int r = 0; r < 4; ++r) av[r] = *(const float4*)&A[(4 * ti + r) * SA + m];
        #pragma unroll
        for (int c = 0; c < 4; ++c) bv[c] = *(const float4*)&B[(4 * tj + c) * SB + m];
        #pragma unroll
        for (int r = 0; r < 4; ++r)
            #pragma unroll
            for (int c = 0; c < 4; ++c)
                a[r][c] += av[r].x * bv[c].x + av[r].y * bv[c].y
                         + av[r].z * bv[c].z + av[r].w * bv[c].w;
    }
}

// Newton-Schulz (classic, for b0/b2): X <- X(2I - M X), X0 = alpha*I.
// First iteration analytic: X1 = 2a*I - a^2*M. sM stride SM; sX pad; sY flat
template<int SM>
__device__ __forceinline__ void ns_invert(const float* sM, float* sX, float* sY,
                                          int iters, int ti, int tj,
                                          int tid, float alpha)
{
    const float a2 = alpha * alpha;
    for (int idx = tid; idx < 4096; idx += 256) {
        int i = idx >> 6, j = idx & 63;
        sX[i * LDP + j] = ((i == j) ? 2.f * alpha : 0.f) - a2 * sM[i * SM + j];
    }
    __syncthreads();
    for (int it = 1; it < iters; ++it) {
        float y[4][4] = {};
        mm64<SM, LDP>(sM, sX, ti, tj, y);          // Y = M*X
        #pragma unroll
        for (int r = 0; r < 4; ++r) {
            float4 v = {y[r][0], y[r][1], y[r][2], y[r][3]};
            *(float4*)&sY[(4 * ti + r) * 64 + 4 * tj] = v;
        }
        __syncthreads();
        float z[4][4] = {};
        mm64<LDP, 64>(sX, sY, ti, tj, z);           // Z = X*Y
        __syncthreads();
        #pragma unroll
        for (int r = 0; r < 4; ++r) {
            float4 xv = *(const float4*)&sX[(4 * ti + r) * LDP + 4 * tj];
            xv.x = 2.f * xv.x - z[r][0];
            xv.y = 2.f * xv.y - z[r][1];
            xv.z = 2.f * xv.z - z[r][2];
            xv.w = 2.f * xv.w - z[r][3];
            *(float4*)&sX[(4 * ti + r) * LDP + 4 * tj] = xv;
        }
        __syncthreads();
    }
}

// Residual-form NS fused pass: Xd = Xs + Xs*Rs ; (DOR) Rd = Rs*Rs.
// Shares the B-operand (Rs) between both products: 12 LDS reads per 4-k
// instead of 16 -> 1.5 mm64-equiv for two matmuls. Ends with barrier.
template<bool DOR>
__device__ __forceinline__ void ns_pass(const float* Xs, const float* Rs,
                                        float* Xd, float* Rd, int ti, int tj)
{
    float xr[4][4] = {}, rr[4][4] = {};
    #pragma unroll 4
    for (int k = 0; k < 64; k += 4) {
        float4 xa[4], ra[4];
        #pragma unroll
        for (int r = 0; r < 4; ++r) {
            xa[r] = *(const float4*)&Xs[(4 * ti + r) * LDP + k];
            if (DOR) ra[r] = *(const float4*)&Rs[(4 * ti + r) * LDP + k];
        }
        #pragma unroll
        for (int q = 0; q < 4; ++q) {
            float4 bv = *(const float4*)&Rs[(k + q) * LDP + 4 * tj];
            #pragma unroll
            for (int r = 0; r < 4; ++r) {
                FMA4(xr[r], COMP(xa[r], q), bv);
                if (DOR) FMA4(rr[r], COMP(ra[r], q), bv);
            }
        }
    }
    #pragma unroll
    for (int r = 0; r < 4; ++r) {
        float4 xo = *(const float4*)&Xs[(4 * ti + r) * LDP + 4 * tj];
        float4 xn = {xo.x + xr[r][0], xo.y + xr[r][1],
                     xo.z + xr[r][2], xo.w + xr[r][3]};
        *(float4*)&Xd[(4 * ti + r) * LDP + 4 * tj] = xn;
        if (DOR) {
            float4 rv = {rr[r][0], rr[r][1], rr[r][2], rr[r][3]};
            *(float4*)&Rd[(4 * ti + r) * LDP + 4 * tj] = rv;
        }
    }
    __syncthreads();
}

// ---- device-scope producer/consumer handoff ------------------------------
__device__ __forceinline__ void wait_ge(int* flag, int target, int tid) {
    if (tid == 0) {
        while (__hip_atomic_load(flag, __ATOMIC_ACQUIRE, __HIP_MEMORY_SCOPE_AGENT) < target)
            __builtin_amdgcn_s_sleep(8);
    }
    __syncthreads();
    __threadfence();
}

__device__ __forceinline__ void signal_one(int* flag, int tid) {
    __syncthreads();
    __threadfence();
    if (tid == 0)
        (void)__hip_atomic_fetch_add(flag, 1, __ATOMIC_RELEASE, __HIP_MEMORY_SCOPE_AGENT);
}

// ---------------- single fused kernel, 247 co-resident blocks, 256 thr ----
// 0..159  : A-gemm  (gx=bid&3 col, gy=bid>>2 over GYS_A k-strides, 2 chunks)
// 160..235: Fy-gemm (gx=(bid-160)&3, gy=(bid-160)>>2 over GYS_F, 4-5 chunks)
// 236..239: G1 chunk ch = A_ch A_ch^T -> atomicAdd (waits flags[ch]==GYS_A)
// 240..243: FyAT chunk ch -> atomicAdd (waits flags[ch], flags[4+ch])
// 244: b0 sy chain   245: b2 sx chain
// 246: solve = Frobenius + residual-NS(G1) + free-X1 + 2 full Richardson
__global__ __launch_bounds__(256, 1) void fused_fmnet(
    const float* __restrict__ fx, const float* __restrict__ fy,
    const float* __restrict__ ex, const float* __restrict__ ey,
    const float* __restrict__ tx, const float* __restrict__ ty,
    const float* __restrict__ sx, const float* __restrict__ sy,
    float* __restrict__ ws, float* __restrict__ out)
{
    extern __shared__ __align__(16) float lds[];
    int* flags = (int*)(ws + WS_FLAGS);
    const int tid = threadIdx.x;
    const int ti = tid >> 4, tj = tid & 15;
    const int bid = blockIdx.x;

    if (bid < 236) {
        // ---------------- GEMM: 64x64 (mat,m0) tile, k-strided by gy ----
        float* sT = lds;            // sT[v][k] (transposed stage)
        float* sF = lds + 4352;     // sF[v][m]
        int mat, gx, gy, gstride;
        if (bid < 160) { mat = 0; gx = bid & 3; gy = bid >> 2; gstride = GYS_A; }
        else { int b2 = bid - 160; mat = 1; gx = b2 & 3; gy = b2 >> 2; gstride = GYS_F; }
        const int m0 = gx << 6;
        const float* __restrict__ T = mat ? ty : tx;
        const float* __restrict__ F = mat ? fy : fx;
        float* __restrict__ Out = ws + (mat ? WS_FY : WS_A);

        float4 tv[4], fv[4];
        int sc = gy;
        int vlen = 5000 - (sc << 6); if (vlen > 64) vlen = 64;
        #pragma unroll
        for (int w = 0; w < 4; ++w) {
            const int fidx = tid + (w << 8);
            const int row = fidx >> 4, q = fidx & 15, vv = q << 2;
            if (vv < vlen) tv[w] = *(const float4*)(T + (size_t)row * 5000 + (sc << 6) + vv);
            if (row < vlen) fv[w] = *(const float4*)(F + (size_t)((sc << 6) + row) * 256 + m0 + (q << 2));
        }
        #pragma unroll
        for (int w = 0; w < 4; ++w) {
            const int fidx = tid + (w << 8);
            const int row = fidx >> 4, q = fidx & 15, vv = q << 2;
            if (vv < vlen) {
                sT[(vv + 0) * LDP + row] = tv[w].x;
                sT[(vv + 1) * LDP + row] = tv[w].y;
                sT[(vv + 2) * LDP + row] = tv[w].z;
                sT[(vv + 3) * LDP + row] = tv[w].w;
            }
            if (row < vlen) *(float4*)&sF[row * LDP + (q << 2)] = fv[w];
        }
        __syncthreads();

        float acc[4][4] = {};
        for (;;) {
            const int nsc = sc + gstride;
            int nvlen = 5000 - (nsc << 6);
            if (nvlen > 64) nvlen = 64;
            if (nvlen > 0) {   // prefetch next chunk into regs
                #pragma unroll
                for (int w = 0; w < 4; ++w) {
                    const int fidx = tid + (w << 8);
                    const int row = fidx >> 4, q = fidx & 15, vv = q << 2;
                    if (vv < nvlen) tv[w] = *(const float4*)(T + (size_t)row * 5000 + (nsc << 6) + vv);
                    if (row < nvlen) fv[w] = *(const float4*)(F + (size_t)((nsc << 6) + row) * 256 + m0 + (q << 2));
                }
            }
            #pragma unroll 4
            for (int v = 0; v < vlen; ++v) {
                float4 av = *(const float4*)&sT[v * LDP + 4 * ti];
                float4 bv = *(const float4*)&sF[v * LDP + 4 * tj];
                FMA4(acc[0], av.x, bv); FMA4(acc[1], av.y, bv);
                FMA4(acc[2], av.z, bv); FMA4(acc[3], av.w, bv);
            }
            if (nvlen <= 0) break;
            __syncthreads();
            #pragma unroll
            for (int w = 0; w < 4; ++w) {
                const int fidx = tid + (w << 8);
                const int row = fidx >> 4, q = fidx & 15, vv = q << 2;
                if (vv < nvlen) {
                    sT[(vv + 0) * LDP + row] = tv[w].x;
                    sT[(vv + 1) * LDP + row] = tv[w].y;
                    sT[(vv + 2) * LDP + row] = tv[w].z;
                    sT[(vv + 3) * LDP + row] = tv[w].w;
                }
                if (row < nvlen) *(float4*)&sF[row * LDP + (q << 2)] = fv[w];
            }
            __syncthreads();
            sc = nsc; vlen = nvlen;
        }
        #pragma unroll
        for (int r = 0; r < 4; ++r)
            #pragma unroll
            for (int c = 0; c < 4; ++c)
                atomicAdd(&Out[(4 * ti + r) * 256 + m0 + 4 * tj + c], acc[r][c]);
        __syncthreads();
        __threadfence();
        if (tid == 0)
            (void)__hip_atomic_fetch_add(&flags[mat * 4 + gx], 1, __ATOMIC_RELEASE, __HIP_MEMORY_SCOPE_AGENT);
    } else if (bid < 240) {
        // ---------------- G1 chunk: A_ch A_ch^T -> atomicAdd WS_G1 ----
        const int ch = bid - 236;
        wait_ge(&flags[ch], GYS_A, tid);
        float* sA = lds;             // pad
        for (int idx = tid; idx < 1024; idx += 256) {
            int i = idx >> 4, m4 = (idx & 15) << 2;
            *(float4*)&sA[i * LDP + m4] =
                *(const float4*)&ws[WS_A + i * 256 + (ch << 6) + m4];
        }
        __syncthreads();
        float a[4][4] = {};
        mmdot<LDP, LDP>(sA, sA, ti, tj, a);
        #pragma unroll
        for (int r = 0; r < 4; ++r)
            #pragma unroll
            for (int c = 0; c < 4; ++c)
                atomicAdd(&ws[WS_G1 + (4 * ti + r) * 64 + 4 * tj + c], a[r][c]);
        __syncthreads();
        __threadfence();
        if (tid == 0)
            (void)__hip_atomic_fetch_add(&flags[8], 1, __ATOMIC_RELEASE, __HIP_MEMORY_SCOPE_AGENT);
    } else if (bid < 244) {
        // ---------------- FyAT chunk: Fy_ch A_ch^T -> atomicAdd WS_FYAT ----
        const int ch = bid - 240;
        wait_ge(&flags[ch], GYS_A, tid);
        wait_ge(&flags[4 + ch], GYS_F, tid);
        float* sFy = lds;            // pad
        float* sAx = lds + 4352;     // pad
        for (int idx = tid; idx < 1024; idx += 256) {
            int i = idx >> 4, m4 = (idx & 15) << 2;
            *(float4*)&sFy[i * LDP + m4] = *(const float4*)&ws[WS_FY + i * 256 + (ch << 6) + m4];
            *(float4*)&sAx[i * LDP + m4] = *(const float4*)&ws[WS_A  + i * 256 + (ch << 6) + m4];
        }
        __syncthreads();
        float a[4][4] = {};
        mmdot<LDP, LDP>(sFy, sAx, ti, tj, a);
        #pragma unroll
        for (int r = 0; r < 4; ++r)
            #pragma unroll
            for (int c = 0; c < 4; ++c)
                atomicAdd(&ws[WS_FYAT + (4 * ti + r) * 64 + 4 * tj + c], a[r][c]);
        signal_one(&flags[9], tid);
    } else if (bid == 244) {
        // ---------------- b0: sy chain (no deps) ----------------
        float* sSy = lds;            // pad: sy, later Hinv
        float* sXx = lds + 4352;     // pad: NS X -> Sinv
        float* sYy = lds + 8704;     // flat: NS tmp
        float* sH  = lds + 12800;    // flat: H1
        float* sV  = lds + 16896;    // ey
        for (int idx = tid; idx < 1024; idx += 256) {
            int i = idx >> 4, j4 = (idx & 15) << 2;
            *(float4*)&sSy[i * LDP + j4] = *(const float4*)&sy[i * 64 + j4];
        }
        if (tid < 64) sV[tid] = ey[tid];
        __syncthreads();
        // H1 = sy^T sy (column outer-product)
        {
            float h[4][4] = {};
            for (int k = 0; k < 64; ++k) {
                float4 av = *(const float4*)&sSy[k * LDP + 4 * ti];
                float4 bv = *(const float4*)&sSy[k * LDP + 4 * tj];
                FMA4(h[0], av.x, bv); FMA4(h[1], av.y, bv);
                FMA4(h[2], av.z, bv); FMA4(h[3], av.w, bv);
            }
            #pragma unroll
            for (int r = 0; r < 4; ++r) {
                float4 v = {h[r][0], h[r][1], h[r][2], h[r][3]};
                *(float4*)&sH[(4 * ti + r) * 64 + 4 * tj] = v;
            }
        }
        __syncthreads();
        ns_invert<LDP>(sSy, sXx, sYy, NS_SY, ti, tj, tid, 1.0f);   // Sinv
        // Hinv = Sinv Sinv^T -> overwrite sSy
        {
            float h[4][4] = {};
            mmdot<LDP, LDP>(sXx, sXx, ti, tj, h);
            __syncthreads();
            #pragma unroll
            for (int r = 0; r < 4; ++r) {
                float4 v = {h[r][0], h[r][1], h[r][2], h[r][3]};
                *(float4*)&sSy[(4 * ti + r) * LDP + 4 * tj] = v;
            }
        }
        __syncthreads();
        // C = Hinv * (D H1)
        {
            float a[4][4] = {};
            #pragma unroll 4
            for (int k = 0; k < 64; k += 4) {
                float4 av[4];
                #pragma unroll
                for (int r = 0; r < 4; ++r) av[r] = *(const float4*)&sSy[(4 * ti + r) * LDP + k];
                #pragma unroll
                for (int q = 0; q < 4; ++q) {
                    float e = sV[k + q];
                    float4 bv = *(const float4*)&sH[(k + q) * 64 + 4 * tj];
                    bv.x *= e; bv.y *= e; bv.z *= e; bv.w *= e;
                    #pragma unroll
                    for (int r = 0; r < 4; ++r) FMA4(a[r], COMP(av[r], q), bv);
                }
            }
            #pragma unroll
            for (int r = 0; r < 4; ++r) {
                float4 v = {a[r][0], a[r][1], a[r][2], a[r][3]};
                *(float4*)&ws[WS_C + (4 * ti + r) * 64 + 4 * tj] = v;
            }
        }
        signal_one(&flags[9], tid);
    } else if (bid == 245) {
        // ---------------- b2: sx chain (no deps) ----------------
        float* sM = lds;             // pad: sx
        float* sX = lds + 4352;      // pad: P
        float* sY = lds + 8704;      // flat
        float* sV = lds + 12800;     // ex
        for (int idx = tid; idx < 1024; idx += 256) {
            int i = idx >> 4, j4 = (idx & 15) << 2;
            *(float4*)&sM[i * LDP + j4] = *(const float4*)&sx[i * 64 + j4];
        }
        if (tid < 64) sV[tid] = ex[tid];
        __syncthreads();
        ns_invert<LDP>(sM, sX, sY, NS_SX, ti, tj, tid, 1.0f);
        float aR2[4][4] = {}, aR4[4][4] = {}, aT1[4][4] = {};
        for (int k = 0; k < 64; ++k) {
            float e = sV[k], e2 = e * e;
            float4 av = *(const float4*)&sX[k * LDP + 4 * ti];
            float4 bv = *(const float4*)&sX[k * LDP + 4 * tj];
            float avv[4] = {av.x, av.y, av.z, av.w};
            #pragma unroll
            for (int r = 0; r < 4; ++r) {
                FMA4(aR4[r], avv[r], bv);
                float ea = e * avv[r];
                FMA4(aR2[r], ea, bv);
                float e2a = e2 * avv[r];
                FMA4(aT1[r], e2a, bv);
            }
        }
        #pragma unroll
        for (int r = 0; r < 4; ++r) {
            int o = (4 * ti + r) * 64 + 4 * tj;
            float4 v2 = {aR2[r][0], aR2[r][1], aR2[r][2], aR2[r][3]};
            float4 v4 = {aR4[r][0], aR4[r][1], aR4[r][2], aR4[r][3]};
            float4 v1 = {aT1[r][0], aT1[r][1], aT1[r][2], aT1[r][3]};
            *(float4*)&ws[WS_R2 + o] = v2;
            *(float4*)&ws[WS_R4 + o] = v4;
            *(float4*)&ws[WS_T1 + o] = v1;
        }
        signal_one(&flags[9], tid);
    } else {
        // ---------------- solve: residual-NS(G1) + free-X1 + Richardson ----
        //   sM  0      flat 4096 : G1 -> M1 (in place)
        //   P1  4096   pad  4352 : Frob scratch / R1,R3 / FyAT-stage,E2,W
        //   P2  8448   pad  4352 : R0,R2,R4 / C
        //   P3  12800  pad  4352 : X1,X3,X5=Ginv (in place)
        //   P4  17152  pad  4352 : X2,X4 / Richardson X
        //   cR2 21504  flat 4096
        //   cR4 25600  flat 4096
        float* sM  = lds;
        float* P1  = lds + 4096;
        float* P2  = lds + 8448;
        float* P3  = lds + 12800;
        float* P4  = lds + 17152;
        float* cR2 = lds + 21504;
        float* cR4 = lds + 25600;

        wait_ge(&flags[8], 4, tid);      // G1 complete
        for (int idx = tid; idx < 1024; idx += 256) {
            int i = idx >> 4, j4 = (idx & 15) << 2;
            *(float4*)&sM[i * 64 + j4] = *(const float4*)&ws[WS_G1 + i * 64 + j4];
        }
        __syncthreads();
        // Frobenius-optimal alpha = tr(G1)/||G1||_F^2 (scratch in P1)
        if (tid < 64) {
            float s = 0.f;
            for (int j4 = 0; j4 < 64; j4 += 4) {
                float4 v = *(const float4*)&sM[tid * 64 + j4];
                s += v.x * v.x + v.y * v.y + v.z * v.z + v.w * v.w;
            }
            P1[tid] = s;
            P1[64 + tid] = sM[tid * 64 + tid];
        }
        __syncthreads();
        float f2 = 0.f, tr = 0.f;
        for (int i = 0; i < 64; ++i) { f2 += P1[i]; tr += P1[64 + i]; }
        const float alpha = tr / f2, a2 = alpha * alpha;
        // analytic: X1 = 2a I - a^2 G -> P3 ; R0 = I - a G -> P2
        for (int idx = tid; idx < 4096; idx += 256) {
            int i = idx >> 6, j = idx & 63;
            float g = sM[i * 64 + j];
            float d = (i == j) ? 1.f : 0.f;
            P3[i * LDP + j] = 2.f * alpha * d - a2 * g;
            P2[i * LDP + j] = d - alpha * g;
        }
        __syncthreads();
        // R1 = R0^2 -> P1
        {
            float z[4][4] = {};
            mm64<LDP, LDP>(P2, P2, ti, tj, z);
            #pragma unroll
            for (int r = 0; r < 4; ++r) {
                float4 v = {z[r][0], z[r][1], z[r][2], z[r][3]};
                *(float4*)&P1[(4 * ti + r) * LDP + 4 * tj] = v;
            }
            __syncthreads();
        }
        // fused residual-NS: X_{k+1}=X_k(I+R_k), R_{k+1}=R_k^2 (last skips R)
        ns_pass<true >(P3, P1, P4, P2, ti, tj);   // X2->P4, R2->P2
        ns_pass<true >(P4, P2, P3, P1, ti, tj);   // X3->P3, R3->P1
        ns_pass<true >(P3, P1, P4, P2, ti, tj);   // X4->P4, R4->P2
        ns_pass<false>(P4, P2, P3, P3, ti, tj);   // X5 = Ginv -> P3 (in place)

        wait_ge(&flags[9], 6, tid);      // b0, b2, 4 FyAT chunks done
        // stage: M1 = G1 + l*T1 (in place); R2,R4 flats; C->P2; FyAT->P1
        for (int idx = tid; idx < 1024; idx += 256) {
            int i = idx >> 4, j4 = (idx & 15) << 2;
            int o = i * 64 + j4;
            float4 gv = *(const float4*)&sM[o];
            float4 t = *(const float4*)&ws[WS_T1 + o];
            gv.x = fmaf(LMBDA, t.x, gv.x); gv.y = fmaf(LMBDA, t.y, gv.y);
            gv.z = fmaf(LMBDA, t.z, gv.z); gv.w = fmaf(LMBDA, t.w, gv.w);
            *(float4*)&sM[o] = gv;
            *(float4*)&cR2[o] = *(const float4*)&ws[WS_R2 + o];
            *(float4*)&cR4[o] = *(const float4*)&ws[WS_R4 + o];
            *(float4*)&P2[i * LDP + j4] = *(const float4*)&ws[WS_C + o];
            *(float4*)&P1[i * LDP + j4] = *(const float4*)&ws[WS_FYAT + o];
        }
        float4 eyv = *(const float4*)&ey[4 * ti];
        float eyr[4] = {eyv.x, eyv.y, eyv.z, eyv.w};
        float leyr[4];
        #pragma unroll
        for (int r = 0; r < 4; ++r) leyr[r] = LMBDA * eyr[r];

        float fyr[4][4], xreg[4][4];
        #pragma unroll
        for (int r = 0; r < 4; ++r) {
            float4 v = *(const float4*)&ws[WS_FYAT + (4 * ti + r) * 64 + 4 * tj];
            fyr[r][0] = v.x; fyr[r][1] = v.y; fyr[r][2] = v.z; fyr[r][3] = v.w;
        }
        __syncthreads();

        // free iteration 0: X1 = FyAT * Ginv (exact: grp1/grp2 vanish at X=0)
        {
            float dX[4][4] = {};
            mm64<LDP, LDP>(P1, P3, ti, tj, dX);
            #pragma unroll
            for (int r = 0; r < 4; ++r) {
                #pragma unroll
                for (int c = 0; c < 4; ++c) xreg[r][c] = dX[r][c];
                float4 v = {xreg[r][0], xreg[r][1], xreg[r][2], xreg[r][3]};
                *(float4*)&P4[(4 * ti + r) * LDP + 4 * tj] = v;
            }
        }
        __syncthreads();

        float E1[4][4];
        for (int it = 0; it < OUTER_FULL; ++it) {
            // grp1: Sm=X*M1, S2=X*R2, S4=X*R4 (shared A-reads)
            {
                float Sm[4][4] = {}, S2[4][4] = {}, S4[4][4] = {};
                #pragma unroll 2
                for (int k = 0; k < 64; k += 4) {
                    float4 av[4];
                    #pragma unroll
                    for (int r = 0; r < 4; ++r)
                        av[r] = *(const float4*)&P4[(4 * ti + r) * LDP + k];
                    #pragma unroll
                    for (int q = 0; q < 4; ++q) {
                        float4 mv = *(const float4*)&sM[(k + q) * 64 + 4 * tj];
                        float4 qv = *(const float4*)&cR2[(k + q) * 64 + 4 * tj];
                        float4 rv = *(const float4*)&cR4[(k + q) * 64 + 4 * tj];
                        #pragma unroll
                        for (int r = 0; r < 4; ++r) {
                            float x = COMP(av[r], q);
                            FMA4(Sm[r], x, mv);
                            FMA4(S2[r], x, qv);
                            FMA4(S4[r], x, rv);
                        }
                    }
                }
                __syncthreads();   // all FyAT/E2 reads of P1 done before overwrite
                #pragma unroll
                for (int r = 0; r < 4; ++r) {
                    float4 e2;
                    e2.x = LMBDA * fmaf(eyr[r], S4[r][0], -S2[r][0]);
                    e2.y = LMBDA * fmaf(eyr[r], S4[r][1], -S2[r][1]);
                    e2.z = LMBDA * fmaf(eyr[r], S4[r][2], -S2[r][2]);
                    e2.w = LMBDA * fmaf(eyr[r], S4[r][3], -S2[r][3]);
                    *(float4*)&P1[(4 * ti + r) * LDP + 4 * tj] = e2;
                    #pragma unroll
                    for (int c = 0; c < 4; ++c)
                        E1[r][c] = fmaf(-leyr[r], S2[r][c], Sm[r][c]);
                }
            }
            __syncthreads();
            // grp2: Z = C*E2 ; then W = FyAT - E1 - Z -> P1 (overwrites E2)
            {
                float Z[4][4] = {};
                mm64<LDP, LDP>(P2, P1, ti, tj, Z);
                __syncthreads();   // all E2 reads done before W overwrite
                #pragma unroll
                for (int r = 0; r < 4; ++r) {
                    float4 w;
                    w.x = fyr[r][0] - E1[r][0] - Z[r][0];
                    w.y = fyr[r][1] - E1[r][1] - Z[r][1];
                    w.z = fyr[r][2] - E1[r][2] - Z[r][2];
                    w.w = fyr[r][3] - E1[r][3] - Z[r][3];
                    *(float4*)&P1[(4 * ti + r) * LDP + 4 * tj] = w;
                }
            }
            __syncthreads();
            // grp3: dX = W*Ginv ; X += dX
            {
                float dX[4][4] = {};
                mm64<LDP, LDP>(P1, P3, ti, tj, dX);
                #pragma unroll
                for (int r = 0; r < 4; ++r) {
                    float4 v;
                    #pragma unroll
                    for (int c = 0; c < 4; ++c) xreg[r][c] += dX[r][c];
                    v.x = xreg[r][0]; v.y = xreg[r][1]; v.z = xreg[r][2]; v.w = xreg[r][3];
                    *(float4*)&P4[(4 * ti + r) * LDP + 4 * tj] = v;
                    if (it == OUTER_FULL - 1)
                        *(float4*)&out[(4 * ti + r) * 64 + 4 * tj] = v;
                }
            }
            if (it == OUTER_FULL - 1) break;
            __syncthreads();
        }
    }
}

extern "C" void kernel_launch(void* const* d_in, const int* in_sizes, int n_in,
                              void* d_out, int out_size, void* d_ws, size_t ws_size,
                              hipStream_t stream) {
    (void)in_sizes; (void)n_in; (void)out_size; (void)ws_size;
    const float* fx = (const float*)d_in[0];
    const float* fy = (const float*)d_in[1];
    const float* ex = (const float*)d_in[2];
    const float* ey = (const float*)d_in[3];
    const float* tx = (const float*)d_in[4];
    const float* ty = (const float*)d_in[5];
    const float* sx = (const float*)d_in[6];
    const float* sy = (const float*)d_in[7];
    float* ws = (float*)d_ws;
    float* out = (float*)d_out;

    (void)hipFuncSetAttribute((const void*)fused_fmnet,
                              hipFuncAttributeMaxDynamicSharedMemorySize, 134144);

    // zero A/Fy/G1/FyAT accumulators + flags
    (void)hipMemsetAsync(d_ws, 0, (size_t)(WS_T1) * sizeof(float), stream);
    (void)hipMemsetAsync((char*)d_ws + (size_t)WS_FLAGS * sizeof(float), 0, 64, stream);
    fused_fmnet<<<247, 256, 134144, stream>>>(fx, fy, ex, ey, tx, ty, sx, sy, ws, out);
}

// Round 9
// 166.818 us; speedup vs baseline: 1.1077x; 1.0083x over previous
//
#include <hip/hip_runtime.h>

#define LMBDA 0.001f
#define NS_SY 4      // NS iters for inv(sy) (first iter analytic)
#define NS_SX 5      // NS iters for inv(sx) (first iter analytic)
#define OUTER_FULL 2 // full Richardson iters after free X1 = FyAT*Ginv (== old OUTER=3)
#define LDP 68       // padded stride
#define GYS_A 40     // A-gemm k-strides (160 blocks, 2 chunks each) — A gates the serial chain
#define GYS_F 19     // Fy-gemm k-strides (76 blocks, 4-5 chunks) — FyAT needed ~20us later

// workspace layout (float offsets) — [0, 40976) is ONE contiguous memset region
// (accumulators + flags); T1/R2/R4/C are write-before-read, never zeroed.
#define WS_A    0        // 64*256 (atomic-accumulated)
#define WS_FY   16384    // 64*256 (atomic-accumulated)
#define WS_G1   32768    // 64*64  (atomic-accumulated by 4 chunk blocks)
#define WS_FYAT 36864    // 64*64  (atomic-accumulated by 4 chunk blocks)
#define WS_FLAGS 40960   // 16 ints: [0..3] A cols (GYS_A) [4..7] Fy cols (GYS_F)
                         //          [8] G1 chunks (4) [9] preps (6)
#define WS_T1   40976
#define WS_R2   45072
#define WS_R4   49168
#define WS_C    53264

#define FMA4(ar, xs, b) { ar[0]=fmaf((xs),(b).x,ar[0]); ar[1]=fmaf((xs),(b).y,ar[1]); \
                          ar[2]=fmaf((xs),(b).z,ar[2]); ar[3]=fmaf((xs),(b).w,ar[3]); }
#define COMP(v,q) ((q)==0?(v).x:((q)==1?(v).y:((q)==2?(v).z:(v).w)))

// C-tile += A[4ti..][:] * B[:][4tj..]; all f4 (b128) LDS reads
template<int SA, int SB>
__device__ __forceinline__ void mm64(const float* __restrict__ A,
                                     const float* __restrict__ B,
                                     int ti, int tj, float a[4][4]) {
    #pragma unroll 4
    for (int k = 0; k < 64; k += 4) {
        float4 av0 = *(const float4*)&A[(4 * ti + 0) * SA + k];
        float4 av1 = *(const float4*)&A[(4 * ti + 1) * SA + k];
        float4 av2 = *(const float4*)&A[(4 * ti + 2) * SA + k];
        float4 av3 = *(const float4*)&A[(4 * ti + 3) * SA + k];
        float4 b0 = *(const float4*)&B[(k + 0) * SB + 4 * tj];
        float4 b1 = *(const float4*)&B[(k + 1) * SB + 4 * tj];
        float4 b2 = *(const float4*)&B[(k + 2) * SB + 4 * tj];
        float4 b3 = *(const float4*)&B[(k + 3) * SB + 4 * tj];
        FMA4(a[0], av0.x, b0); FMA4(a[0], av0.y, b1); FMA4(a[0], av0.z, b2); FMA4(a[0], av0.w, b3);
        FMA4(a[1], av1.x, b0); FMA4(a[1], av1.y, b1); FMA4(a[1], av1.z, b2); FMA4(a[1], av1.w, b3);
        FMA4(a[2], av2.x, b0); FMA4(a[2], av2.y, b1); FMA4(a[2], av2.z, b2); FMA4(a[2], av2.w, b3);
        FMA4(a[3], av3.x, b0); FMA4(a[3], av3.y, b1); FMA4(a[3], av3.z, b2); FMA4(a[3], av3.w, b3);
    }
}

// dot-style 4x4: a[r][c] += A[4ti+r][:] . B[4tj+c][:]
template<int SA, int SB>
__device__ __forceinline__ void mmdot(const float* __restrict__ A,
                                      const float* __restrict__ B,
                                      int ti, int tj, float a[4][4]) {
    #pragma unroll 4
    for (int m = 0; m < 64; m += 4) {
        float4 av[4], bv[4];
        #pragma unroll
        for (int r = 0; r < 4; ++r) av[r] = *(const float4*)&A[(4 * ti + r) * SA + m];
        #pragma unroll
        for (int c = 0; c < 4; ++c) bv[c] = *(const float4*)&B[(4 * tj + c) * SB + m];
        #pragma unroll
        for (int r = 0; r < 4; ++r)
            #pragma unroll
            for (int c = 0; c < 4; ++c)
                a[r][c] += av[r].x * bv[c].x + av[r].y * bv[c].y
                         + av[r].z * bv[c].z + av[r].w * bv[c].w;
    }
}

// Newton-Schulz (classic, for b0/b2): X <- X(2I - M X), X0 = alpha*I.
// First iteration analytic: X1 = 2a*I - a^2*M. sM stride SM; sX pad; sY flat
template<int SM>
__device__ __forceinline__ void ns_invert(const float* sM, float* sX, float* sY,
                                          int iters, int ti, int tj,
                                          int tid, float alpha)
{
    const float a2 = alpha * alpha;
    for (int idx = tid; idx < 4096; idx += 256) {
        int i = idx >> 6, j = idx & 63;
        sX[i * LDP + j] = ((i == j) ? 2.f * alpha : 0.f) - a2 * sM[i * SM + j];
    }
    __syncthreads();
    for (int it = 1; it < iters; ++it) {
        float y[4][4] = {};
        mm64<SM, LDP>(sM, sX, ti, tj, y);          // Y = M*X
        #pragma unroll
        for (int r = 0; r < 4; ++r) {
            float4 v = {y[r][0], y[r][1], y[r][2], y[r][3]};
            *(float4*)&sY[(4 * ti + r) * 64 + 4 * tj] = v;
        }
        __syncthreads();
        float z[4][4] = {};
        mm64<LDP, 64>(sX, sY, ti, tj, z);           // Z = X*Y
        __syncthreads();
        #pragma unroll
        for (int r = 0; r < 4; ++r) {
            float4 xv = *(const float4*)&sX[(4 * ti + r) * LDP + 4 * tj];
            xv.x = 2.f * xv.x - z[r][0];
            xv.y = 2.f * xv.y - z[r][1];
            xv.z = 2.f * xv.z - z[r][2];
            xv.w = 2.f * xv.w - z[r][3];
            *(float4*)&sX[(4 * ti + r) * LDP + 4 * tj] = xv;
        }
        __syncthreads();
    }
}

// Residual-form NS fused pass: Xd = Xs + Xs*Rs ; (DOR) Rd = Rs*Rs.
// Shares the B-operand (Rs) between both products: 12 LDS reads per 4-k
// instead of 16 -> 1.5 mm64-equiv for two matmuls. Ends with barrier.
template<bool DOR>
__device__ __forceinline__ void ns_pass(const float* Xs, const float* Rs,
                                        float* Xd, float* Rd, int ti, int tj)
{
    float xr[4][4] = {}, rr[4][4] = {};
    #pragma unroll 4
    for (int k = 0; k < 64; k += 4) {
        float4 xa[4], ra[4];
        #pragma unroll
        for (int r = 0; r < 4; ++r) {
            xa[r] = *(const float4*)&Xs[(4 * ti + r) * LDP + k];
            if (DOR) ra[r] = *(const float4*)&Rs[(4 * ti + r) * LDP + k];
        }
        #pragma unroll
        for (int q = 0; q < 4; ++q) {
            float4 bv = *(const float4*)&Rs[(k + q) * LDP + 4 * tj];
            #pragma unroll
            for (int r = 0; r < 4; ++r) {
                FMA4(xr[r], COMP(xa[r], q), bv);
                if (DOR) FMA4(rr[r], COMP(ra[r], q), bv);
            }
        }
    }
    #pragma unroll
    for (int r = 0; r < 4; ++r) {
        float4 xo = *(const float4*)&Xs[(4 * ti + r) * LDP + 4 * tj];
        float4 xn = {xo.x + xr[r][0], xo.y + xr[r][1],
                     xo.z + xr[r][2], xo.w + xr[r][3]};
        *(float4*)&Xd[(4 * ti + r) * LDP + 4 * tj] = xn;
        if (DOR) {
            float4 rv = {rr[r][0], rr[r][1], rr[r][2], rr[r][3]};
            *(float4*)&Rd[(4 * ti + r) * LDP + 4 * tj] = rv;
        }
    }
    __syncthreads();
}

// ---- device-scope producer/consumer handoff ------------------------------
__device__ __forceinline__ void wait_ge(int* flag, int target, int tid) {
    if (tid == 0) {
        while (__hip_atomic_load(flag, __ATOMIC_ACQUIRE, __HIP_MEMORY_SCOPE_AGENT) < target)
            __builtin_amdgcn_s_sleep(2);
    }
    __syncthreads();
    __threadfence();
}

__device__ __forceinline__ void signal_one(int* flag, int tid) {
    __syncthreads();
    __threadfence();
    if (tid == 0)
        (void)__hip_atomic_fetch_add(flag, 1, __ATOMIC_RELEASE, __HIP_MEMORY_SCOPE_AGENT);
}

// ---------------- single fused kernel, 247 co-resident blocks, 256 thr ----
// 0..159  : A-gemm  (gx=bid&3 col, gy=bid>>2 over GYS_A k-strides, 2 chunks)
// 160..235: Fy-gemm (gx=(bid-160)&3, gy=(bid-160)>>2 over GYS_F, 4-5 chunks)
// 236..239: G1 chunk ch = A_ch A_ch^T -> atomicAdd (waits flags[ch]==GYS_A)
// 240..243: FyAT chunk ch -> atomicAdd (waits flags[ch], flags[4+ch])
// 244: b0 sy chain   245: b2 sx chain
// 246: solve = Frobenius + residual-NS(G1) + free-X1 + 2 full Richardson
__global__ __launch_bounds__(256, 1) void fused_fmnet(
    const float* __restrict__ fx, const float* __restrict__ fy,
    const float* __restrict__ ex, const float* __restrict__ ey,
    const float* __restrict__ tx, const float* __restrict__ ty,
    const float* __restrict__ sx, const float* __restrict__ sy,
    float* __restrict__ ws, float* __restrict__ out)
{
    extern __shared__ __align__(16) float lds[];
    int* flags = (int*)(ws + WS_FLAGS);
    const int tid = threadIdx.x;
    const int ti = tid >> 4, tj = tid & 15;
    const int bid = blockIdx.x;

    if (bid < 236) {
        // ---------------- GEMM: 64x64 (mat,m0) tile, k-strided by gy ----
        float* sT = lds;            // sT[v][k] (transposed stage)
        float* sF = lds + 4352;     // sF[v][m]
        int mat, gx, gy, gstride;
        if (bid < 160) { mat = 0; gx = bid & 3; gy = bid >> 2; gstride = GYS_A; }
        else { int b2 = bid - 160; mat = 1; gx = b2 & 3; gy = b2 >> 2; gstride = GYS_F; }
        const int m0 = gx << 6;
        const float* __restrict__ T = mat ? ty : tx;
        const float* __restrict__ F = mat ? fy : fx;
        float* __restrict__ Out = ws + (mat ? WS_FY : WS_A);

        float4 tv[4], fv[4];
        int sc = gy;
        int vlen = 5000 - (sc << 6); if (vlen > 64) vlen = 64;
        #pragma unroll
        for (int w = 0; w < 4; ++w) {
            const int fidx = tid + (w << 8);
            const int row = fidx >> 4, q = fidx & 15, vv = q << 2;
            if (vv < vlen) tv[w] = *(const float4*)(T + (size_t)row * 5000 + (sc << 6) + vv);
            if (row < vlen) fv[w] = *(const float4*)(F + (size_t)((sc << 6) + row) * 256 + m0 + (q << 2));
        }
        #pragma unroll
        for (int w = 0; w < 4; ++w) {
            const int fidx = tid + (w << 8);
            const int row = fidx >> 4, q = fidx & 15, vv = q << 2;
            if (vv < vlen) {
                sT[(vv + 0) * LDP + row] = tv[w].x;
                sT[(vv + 1) * LDP + row] = tv[w].y;
                sT[(vv + 2) * LDP + row] = tv[w].z;
                sT[(vv + 3) * LDP + row] = tv[w].w;
            }
            if (row < vlen) *(float4*)&sF[row * LDP + (q << 2)] = fv[w];
        }
        __syncthreads();

        float acc[4][4] = {};
        for (;;) {
            const int nsc = sc + gstride;
            int nvlen = 5000 - (nsc << 6);
            if (nvlen > 64) nvlen = 64;
            if (nvlen > 0) {   // prefetch next chunk into regs
                #pragma unroll
                for (int w = 0; w < 4; ++w) {
                    const int fidx = tid + (w << 8);
                    const int row = fidx >> 4, q = fidx & 15, vv = q << 2;
                    if (vv < nvlen) tv[w] = *(const float4*)(T + (size_t)row * 5000 + (nsc << 6) + vv);
                    if (row < nvlen) fv[w] = *(const float4*)(F + (size_t)((nsc << 6) + row) * 256 + m0 + (q << 2));
                }
            }
            #pragma unroll 4
            for (int v = 0; v < vlen; ++v) {
                float4 av = *(const float4*)&sT[v * LDP + 4 * ti];
                float4 bv = *(const float4*)&sF[v * LDP + 4 * tj];
                FMA4(acc[0], av.x, bv); FMA4(acc[1], av.y, bv);
                FMA4(acc[2], av.z, bv); FMA4(acc[3], av.w, bv);
            }
            if (nvlen <= 0) break;
            __syncthreads();
            #pragma unroll
            for (int w = 0; w < 4; ++w) {
                const int fidx = tid + (w << 8);
                const int row = fidx >> 4, q = fidx & 15, vv = q << 2;
                if (vv < nvlen) {
                    sT[(vv + 0) * LDP + row] = tv[w].x;
                    sT[(vv + 1) * LDP + row] = tv[w].y;
                    sT[(vv + 2) * LDP + row] = tv[w].z;
                    sT[(vv + 3) * LDP + row] = tv[w].w;
                }
                if (row < nvlen) *(float4*)&sF[row * LDP + (q << 2)] = fv[w];
            }
            __syncthreads();
            sc = nsc; vlen = nvlen;
        }
        #pragma unroll
        for (int r = 0; r < 4; ++r)
            #pragma unroll
            for (int c = 0; c < 4; ++c)
                atomicAdd(&Out[(4 * ti + r) * 256 + m0 + 4 * tj + c], acc[r][c]);
        __syncthreads();
        __threadfence();
        if (tid == 0)
            (void)__hip_atomic_fetch_add(&flags[mat * 4 + gx], 1, __ATOMIC_RELEASE, __HIP_MEMORY_SCOPE_AGENT);
    } else if (bid < 240) {
        // ---------------- G1 chunk: A_ch A_ch^T -> atomicAdd WS_G1 ----
        const int ch = bid - 236;
        wait_ge(&flags[ch], GYS_A, tid);
        float* sA = lds;             // pad
        for (int idx = tid; idx < 1024; idx += 256) {
            int i = idx >> 4, m4 = (idx & 15) << 2;
            *(float4*)&sA[i * LDP + m4] =
                *(const float4*)&ws[WS_A + i * 256 + (ch << 6) + m4];
        }
        __syncthreads();
        float a[4][4] = {};
        mmdot<LDP, LDP>(sA, sA, ti, tj, a);
        #pragma unroll
        for (int r = 0; r < 4; ++r)
            #pragma unroll
            for (int c = 0; c < 4; ++c)
                atomicAdd(&ws[WS_G1 + (4 * ti + r) * 64 + 4 * tj + c], a[r][c]);
        __syncthreads();
        __threadfence();
        if (tid == 0)
            (void)__hip_atomic_fetch_add(&flags[8], 1, __ATOMIC_RELEASE, __HIP_MEMORY_SCOPE_AGENT);
    } else if (bid < 244) {
        // ---------------- FyAT chunk: Fy_ch A_ch^T -> atomicAdd WS_FYAT ----
        const int ch = bid - 240;
        wait_ge(&flags[ch], GYS_A, tid);
        wait_ge(&flags[4 + ch], GYS_F, tid);
        float* sFy = lds;            // pad
        float* sAx = lds + 4352;     // pad
        for (int idx = tid; idx < 1024; idx += 256) {
            int i = idx >> 4, m4 = (idx & 15) << 2;
            *(float4*)&sFy[i * LDP + m4] = *(const float4*)&ws[WS_FY + i * 256 + (ch << 6) + m4];
            *(float4*)&sAx[i * LDP + m4] = *(const float4*)&ws[WS_A  + i * 256 + (ch << 6) + m4];
        }
        __syncthreads();
        float a[4][4] = {};
        mmdot<LDP, LDP>(sFy, sAx, ti, tj, a);
        #pragma unroll
        for (int r = 0; r < 4; ++r)
            #pragma unroll
            for (int c = 0; c < 4; ++c)
                atomicAdd(&ws[WS_FYAT + (4 * ti + r) * 64 + 4 * tj + c], a[r][c]);
        signal_one(&flags[9], tid);
    } else if (bid == 244) {
        // ---------------- b0: sy chain (no deps) ----------------
        float* sSy = lds;            // pad: sy, later Hinv
        float* sXx = lds + 4352;     // pad: NS X -> Sinv
        float* sYy = lds + 8704;     // flat: NS tmp
        float* sH  = lds + 12800;    // flat: H1
        float* sV  = lds + 16896;    // ey
        for (int idx = tid; idx < 1024; idx += 256) {
            int i = idx >> 4, j4 = (idx & 15) << 2;
            *(float4*)&sSy[i * LDP + j4] = *(const float4*)&sy[i * 64 + j4];
        }
        if (tid < 64) sV[tid] = ey[tid];
        __syncthreads();
        // H1 = sy^T sy (column outer-product)
        {
            float h[4][4] = {};
            for (int k = 0; k < 64; ++k) {
                float4 av = *(const float4*)&sSy[k * LDP + 4 * ti];
                float4 bv = *(const float4*)&sSy[k * LDP + 4 * tj];
                FMA4(h[0], av.x, bv); FMA4(h[1], av.y, bv);
                FMA4(h[2], av.z, bv); FMA4(h[3], av.w, bv);
            }
            #pragma unroll
            for (int r = 0; r < 4; ++r) {
                float4 v = {h[r][0], h[r][1], h[r][2], h[r][3]};
                *(float4*)&sH[(4 * ti + r) * 64 + 4 * tj] = v;
            }
        }
        __syncthreads();
        ns_invert<LDP>(sSy, sXx, sYy, NS_SY, ti, tj, tid, 1.0f);   // Sinv
        // Hinv = Sinv Sinv^T -> overwrite sSy
        {
            float h[4][4] = {};
            mmdot<LDP, LDP>(sXx, sXx, ti, tj, h);
            __syncthreads();
            #pragma unroll
            for (int r = 0; r < 4; ++r) {
                float4 v = {h[r][0], h[r][1], h[r][2], h[r][3]};
                *(float4*)&sSy[(4 * ti + r) * LDP + 4 * tj] = v;
            }
        }
        __syncthreads();
        // C = Hinv * (D H1)
        {
            float a[4][4] = {};
            #pragma unroll 4
            for (int k = 0; k < 64; k += 4) {
                float4 av[4];
                #pragma unroll
                for (int r = 0; r < 4; ++r) av[r] = *(const float4*)&sSy[(4 * ti + r) * LDP + k];
                #pragma unroll
                for (int q = 0; q < 4; ++q) {
                    float e = sV[k + q];
                    float4 bv = *(const float4*)&sH[(k + q) * 64 + 4 * tj];
                    bv.x *= e; bv.y *= e; bv.z *= e; bv.w *= e;
                    #pragma unroll
                    for (int r = 0; r < 4; ++r) FMA4(a[r], COMP(av[r], q), bv);
                }
            }
            #pragma unroll
            for (int r = 0; r < 4; ++r) {
                float4 v = {a[r][0], a[r][1], a[r][2], a[r][3]};
                *(float4*)&ws[WS_C + (4 * ti + r) * 64 + 4 * tj] = v;
            }
        }
        signal_one(&flags[9], tid);
    } else if (bid == 245) {
        // ---------------- b2: sx chain (no deps) ----------------
        float* sM = lds;             // pad: sx
        float* sX = lds + 4352;      // pad: P
        float* sY = lds + 8704;      // flat
        float* sV = lds + 12800;     // ex
        for (int idx = tid; idx < 1024; idx += 256) {
            int i = idx >> 4, j4 = (idx & 15) << 2;
            *(float4*)&sM[i * LDP + j4] = *(const float4*)&sx[i * 64 + j4];
        }
        if (tid < 64) sV[tid] = ex[tid];
        __syncthreads();
        ns_invert<LDP>(sM, sX, sY, NS_SX, ti, tj, tid, 1.0f);
        float aR2[4][4] = {}, aR4[4][4] = {}, aT1[4][4] = {};
        for (int k = 0; k < 64; ++k) {
            float e = sV[k], e2 = e * e;
            float4 av = *(const float4*)&sX[k * LDP + 4 * ti];
            float4 bv = *(const float4*)&sX[k * LDP + 4 * tj];
            float avv[4] = {av.x, av.y, av.z, av.w};
            #pragma unroll
            for (int r = 0; r < 4; ++r) {
                FMA4(aR4[r], avv[r], bv);
                float ea = e * avv[r];
                FMA4(aR2[r], ea, bv);
                float e2a = e2 * avv[r];
                FMA4(aT1[r], e2a, bv);
            }
        }
        #pragma unroll
        for (int r = 0; r < 4; ++r) {
            int o = (4 * ti + r) * 64 + 4 * tj;
            float4 v2 = {aR2[r][0], aR2[r][1], aR2[r][2], aR2[r][3]};
            float4 v4 = {aR4[r][0], aR4[r][1], aR4[r][2], aR4[r][3]};
            float4 v1 = {aT1[r][0], aT1[r][1], aT1[r][2], aT1[r][3]};
            *(float4*)&ws[WS_R2 + o] = v2;
            *(float4*)&ws[WS_R4 + o] = v4;
            *(float4*)&ws[WS_T1 + o] = v1;
        }
        signal_one(&flags[9], tid);
    } else {
        // ---------------- solve: residual-NS(G1) + free-X1 + Richardson ----
        //   sM  0      flat 4096 : G1 -> M1 (in place)
        //   P1  4096   pad  4352 : Frob scratch / R1,R3 / FyAT-stage,E2,W
        //   P2  8448   pad  4352 : R0,R2,R4 / C
        //   P3  12800  pad  4352 : X1,X3,X5=Ginv (in place)
        //   P4  17152  pad  4352 : X2,X4 / Richardson X
        //   cR2 21504  flat 4096
        //   cR4 25600  flat 4096
        float* sM  = lds;
        float* P1  = lds + 4096;
        float* P2  = lds + 8448;
        float* P3  = lds + 12800;
        float* P4  = lds + 17152;
        float* cR2 = lds + 21504;
        float* cR4 = lds + 25600;

        wait_ge(&flags[8], 4, tid);      // G1 complete
        for (int idx = tid; idx < 1024; idx += 256) {
            int i = idx >> 4, j4 = (idx & 15) << 2;
            *(float4*)&sM[i * 64 + j4] = *(const float4*)&ws[WS_G1 + i * 64 + j4];
        }
        __syncthreads();
        // Frobenius-optimal alpha = tr(G1)/||G1||_F^2 (scratch in P1)
        if (tid < 64) {
            float s = 0.f;
            for (int j4 = 0; j4 < 64; j4 += 4) {
                float4 v = *(const float4*)&sM[tid * 64 + j4];
                s += v.x * v.x + v.y * v.y + v.z * v.z + v.w * v.w;
            }
            P1[tid] = s;
            P1[64 + tid] = sM[tid * 64 + tid];
        }
        __syncthreads();
        float f2 = 0.f, tr = 0.f;
        for (int i = 0; i < 64; ++i) { f2 += P1[i]; tr += P1[64 + i]; }
        const float alpha = tr / f2, a2 = alpha * alpha;
        // analytic: X1 = 2a I - a^2 G -> P3 ; R0 = I - a G -> P2
        for (int idx = tid; idx < 4096; idx += 256) {
            int i = idx >> 6, j = idx & 63;
            float g = sM[i * 64 + j];
            float d = (i == j) ? 1.f : 0.f;
            P3[i * LDP + j] = 2.f * alpha * d - a2 * g;
            P2[i * LDP + j] = d - alpha * g;
        }
        __syncthreads();
        // R1 = R0^2 -> P1
        {
            float z[4][4] = {};
            mm64<LDP, LDP>(P2, P2, ti, tj, z);
            #pragma unroll
            for (int r = 0; r < 4; ++r) {
                float4 v = {z[r][0], z[r][1], z[r][2], z[r][3]};
                *(float4*)&P1[(4 * ti + r) * LDP + 4 * tj] = v;
            }
            __syncthreads();
        }
        // fused residual-NS: X_{k+1}=X_k(I+R_k), R_{k+1}=R_k^2 (last skips R)
        ns_pass<true >(P3, P1, P4, P2, ti, tj);   // X2->P4, R2->P2
        ns_pass<true >(P4, P2, P3, P1, ti, tj);   // X3->P3, R3->P1
        ns_pass<true >(P3, P1, P4, P2, ti, tj);   // X4->P4, R4->P2
        ns_pass<false>(P4, P2, P3, P3, ti, tj);   // X5 = Ginv -> P3 (in place)

        wait_ge(&flags[9], 6, tid);      // b0, b2, 4 FyAT chunks done
        // stage: M1 = G1 + l*T1 (in place); R2,R4 flats; C->P2; FyAT->P1
        for (int idx = tid; idx < 1024; idx += 256) {
            int i = idx >> 4, j4 = (idx & 15) << 2;
            int o = i * 64 + j4;
            float4 gv = *(const float4*)&sM[o];
            float4 t = *(const float4*)&ws[WS_T1 + o];
            gv.x = fmaf(LMBDA, t.x, gv.x); gv.y = fmaf(LMBDA, t.y, gv.y);
            gv.z = fmaf(LMBDA, t.z, gv.z); gv.w = fmaf(LMBDA, t.w, gv.w);
            *(float4*)&sM[o] = gv;
            *(float4*)&cR2[o] = *(const float4*)&ws[WS_R2 + o];
            *(float4*)&cR4[o] = *(const float4*)&ws[WS_R4 + o];
            *(float4*)&P2[i * LDP + j4] = *(const float4*)&ws[WS_C + o];
            *(float4*)&P1[i * LDP + j4] = *(const float4*)&ws[WS_FYAT + o];
        }
        float4 eyv = *(const float4*)&ey[4 * ti];
        float eyr[4] = {eyv.x, eyv.y, eyv.z, eyv.w};
        float leyr[4];
        #pragma unroll
        for (int r = 0; r < 4; ++r) leyr[r] = LMBDA * eyr[r];

        float fyr[4][4], xreg[4][4];
        #pragma unroll
        for (int r = 0; r < 4; ++r) {
            float4 v = *(const float4*)&ws[WS_FYAT + (4 * ti + r) * 64 + 4 * tj];
            fyr[r][0] = v.x; fyr[r][1] = v.y; fyr[r][2] = v.z; fyr[r][3] = v.w;
        }
        __syncthreads();

        // free iteration 0: X1 = FyAT * Ginv (exact: grp1/grp2 vanish at X=0)
        {
            float dX[4][4] = {};
            mm64<LDP, LDP>(P1, P3, ti, tj, dX);
            #pragma unroll
            for (int r = 0; r < 4; ++r) {
                #pragma unroll
                for (int c = 0; c < 4; ++c) xreg[r][c] = dX[r][c];
                float4 v = {xreg[r][0], xreg[r][1], xreg[r][2], xreg[r][3]};
                *(float4*)&P4[(4 * ti + r) * LDP + 4 * tj] = v;
            }
        }
        __syncthreads();

        float E1[4][4];
        for (int it = 0; it < OUTER_FULL; ++it) {
            // grp1: Sm=X*M1, S2=X*R2, S4=X*R4 (shared A-reads)
            {
                float Sm[4][4] = {}, S2[4][4] = {}, S4[4][4] = {};
                #pragma unroll 2
                for (int k = 0; k < 64; k += 4) {
                    float4 av[4];
                    #pragma unroll
                    for (int r = 0; r < 4; ++r)
                        av[r] = *(const float4*)&P4[(4 * ti + r) * LDP + k];
                    #pragma unroll
                    for (int q = 0; q < 4; ++q) {
                        float4 mv = *(const float4*)&sM[(k + q) * 64 + 4 * tj];
                        float4 qv = *(const float4*)&cR2[(k + q) * 64 + 4 * tj];
                        float4 rv = *(const float4*)&cR4[(k + q) * 64 + 4 * tj];
                        #pragma unroll
                        for (int r = 0; r < 4; ++r) {
                            float x = COMP(av[r], q);
                            FMA4(Sm[r], x, mv);
                            FMA4(S2[r], x, qv);
                            FMA4(S4[r], x, rv);
                        }
                    }
                }
                __syncthreads();   // all FyAT/E2 reads of P1 done before overwrite
                #pragma unroll
                for (int r = 0; r < 4; ++r) {
                    float4 e2;
                    e2.x = LMBDA * fmaf(eyr[r], S4[r][0], -S2[r][0]);
                    e2.y = LMBDA * fmaf(eyr[r], S4[r][1], -S2[r][1]);
                    e2.z = LMBDA * fmaf(eyr[r], S4[r][2], -S2[r][2]);
                    e2.w = LMBDA * fmaf(eyr[r], S4[r][3], -S2[r][3]);
                    *(float4*)&P1[(4 * ti + r) * LDP + 4 * tj] = e2;
                    #pragma unroll
                    for (int c = 0; c < 4; ++c)
                        E1[r][c] = fmaf(-leyr[r], S2[r][c], Sm[r][c]);
                }
            }
            __syncthreads();
            // grp2: Z = C*E2 ; then W = FyAT - E1 - Z -> P1 (overwrites E2)
            {
                float Z[4][4] = {};
                mm64<LDP, LDP>(P2, P1, ti, tj, Z);
                __syncthreads();   // all E2 reads done before W overwrite
                #pragma unroll
                for (int r = 0; r < 4; ++r) {
                    float4 w;
                    w.x = fyr[r][0] - E1[r][0] - Z[r][0];
                    w.y = fyr[r][1] - E1[r][1] - Z[r][1];
                    w.z = fyr[r][2] - E1[r][2] - Z[r][2];
                    w.w = fyr[r][3] - E1[r][3] - Z[r][3];
                    *(float4*)&P1[(4 * ti + r) * LDP + 4 * tj] = w;
                }
            }
            __syncthreads();
            // grp3: dX = W*Ginv ; X += dX
            {
                float dX[4][4] = {};
                mm64<LDP, LDP>(P1, P3, ti, tj, dX);
                #pragma unroll
                for (int r = 0; r < 4; ++r) {
                    float4 v;
                    #pragma unroll
                    for (int c = 0; c < 4; ++c) xreg[r][c] += dX[r][c];
                    v.x = xreg[r][0]; v.y = xreg[r][1]; v.z = xreg[r][2]; v.w = xreg[r][3];
                    *(float4*)&P4[(4 * ti + r) * LDP + 4 * tj] = v;
                    if (it == OUTER_FULL - 1)
                        *(float4*)&out[(4 * ti + r) * 64 + 4 * tj] = v;
                }
            }
            if (it == OUTER_FULL - 1) break;
            __syncthreads();
        }
    }
}

extern "C" void kernel_launch(void* const* d_in, const int* in_sizes, int n_in,
                              void* d_out, int out_size, void* d_ws, size_t ws_size,
                              hipStream_t stream) {
    (void)in_sizes; (void)n_in; (void)out_size; (void)ws_size;
    const float* fx = (const float*)d_in[0];
    const float* fy = (const float*)d_in[1];
    const float* ex = (const float*)d_in[2];
    const float* ey = (const float*)d_in[3];
    const float* tx = (const float*)d_in[4];
    const float* ty = (const float*)d_in[5];
    const float* sx = (const float*)d_in[6];
    const float* sy = (const float*)d_in[7];
    float* ws = (float*)d_ws;
    float* out = (float*)d_out;

    (void)hipFuncSetAttribute((const void*)fused_fmnet,
                              hipFuncAttributeMaxDynamicSharedMemorySize, 134144);

    // ONE memset: A/Fy/G1/FyAT accumulators + flags (contiguous by layout)
    (void)hipMemsetAsync(d_ws, 0, (size_t)(WS_T1) * sizeof(float), stream);
    fused_fmnet<<<247, 256, 134144, stream>>>(fx, fy, ex, ey, tx, ty, sx, sy, ws, out);
}